// Round 1
// baseline (258.033 us; speedup 1.0000x reference)
//
#include <hip/hip_runtime.h>
#include <math.h>

// FluidFlow: 20 Euler steps of g <- (g + (2/(W(1+g)+1)-1)*dt) * mask, N=6144.
// Analytically z == g+1, so the step is elementwise; the 20-step composite
// Phi(g) is a smooth scalar map on [0,1]. D(g)=Phi(g)-g is fit by a degree-5
// Chebyshev polynomial (coefficients decay ~7.3^-k; trunc error ~2e-7 vs the
// 2e-2 threshold), coefficients computed on the HOST at capture time.
//
// R1 shape change: grid-stride-by-constant, 4608 blocks x 256 thr, each
// thread owns 8 independent float4s (fully unrolled). Rationale: baseline
// (36864 WGs, 1 float4/thread) had MLP=1 load in flight per wave and ~37k
// workgroup dispatches; measured ~67us vs ~46us BW roofline (288 MiB at
// ~6.5 TB/s). 8 independent restrict loads per thread let the compiler
// batch global_load_dwordx4s; 8x fewer dispatches shrinks the CP ramp.

#define GN 6144
#define ROW4 (GN / 4)         // 1536 float4 per row
#define NCOEF 6               // degree 5
#define TOTAL4 (GN * GN / 4)  // 9,437,184 float4s
#define NBLK 4608
#define NTHR 256
#define STRIDE (NBLK * NTHR)  // 1,179,648 threads
#define ITERS (TOTAL4 / STRIDE)  // exactly 8, no tail

typedef float v4f __attribute__((ext_vector_type(4)));

struct Coeffs { float c[NCOEF]; };

__global__ __launch_bounds__(NTHR) void apply_map(const float* __restrict__ in,
                                                  float* __restrict__ out,
                                                  Coeffs cf) {
    const int tid = blockIdx.x * NTHR + threadIdx.x;

#pragma unroll
    for (int i = 0; i < ITERS; ++i) {
        const int idx = tid + i * STRIDE;
        v4f v = reinterpret_cast<const v4f*>(in)[idx];

        const int r = idx / ROW4;             // row (magic-mul, const divisor)
        const int c4 = idx - r * ROW4;        // float4-column
        const bool row_int = (r > 0) && (r < GN - 1);

        v4f res;
#pragma unroll
        for (int j = 0; j < 4; ++j) {
            float g = v[j];
            float t = fmaf(2.0f, g, -1.0f);   // [0,1] -> [-1,1]
            float t2 = t + t;
            float b1 = 0.0f, b2 = 0.0f;
#pragma unroll
            for (int k = NCOEF - 1; k >= 1; --k) {
                float b0 = fmaf(t2, b1, cf.c[k] - b2);
                b2 = b1;
                b1 = b0;
            }
            float d = fmaf(t, b1, cf.c[0] - b2);
            res[j] = row_int ? (g + d) : 0.0f;
        }
        if (c4 == 0) res[0] = 0.0f;           // col 0
        if (c4 == ROW4 - 1) res[3] = 0.0f;    // col GN-1
        __builtin_nontemporal_store(res, reinterpret_cast<v4f*>(out) + idx);
    }
}

// Host-side: 20-step Euler with Halley-12 Lambert W, reference-faithful, fp64.
static double phi_minus_g(double g0) {
    double g = g0;
    for (int s = 0; s < 20; ++s) {
        double xi = sqrt(2.0 * (log(g + 1.0) - 0.5 + 1.0));
        double z = exp(xi * xi * 0.5 + 0.5 - 1.0);
        double w = log1p(z);
        for (int it = 0; it < 12; ++it) {
            double ew = exp(w);
            double f = w * ew - z;
            w = w - f / (ew * (w + 1.0) - (w + 2.0) * f / (2.0 * w + 2.0));
        }
        g = g + (2.0 / (w + 1.0) - 1.0) * 0.01;
    }
    return g - g0;
}

extern "C" void kernel_launch(void* const* d_in, const int* in_sizes, int n_in,
                              void* d_out, int out_size, void* d_ws,
                              size_t ws_size, hipStream_t stream) {
    const float* grid = (const float*)d_in[0];
    float* out = (float*)d_out;

    // Project D onto Chebyshev basis with 32 nodes, keep first NCOEF coeffs
    // (near-best approximation; host fp64, deterministic, capture-time).
    const int M = 32;
    double dv[M];
    for (int j = 0; j < M; ++j) {
        double x = cos(M_PI * (j + 0.5) / M);
        dv[j] = phi_minus_g(0.5 * (x + 1.0));
    }
    Coeffs cf;
    for (int k = 0; k < NCOEF; ++k) {
        double s = 0.0;
        for (int j = 0; j < M; ++j)
            s += dv[j] * cos(M_PI * k * (j + 0.5) / M);
        cf.c[k] = (float)(s * (k == 0 ? 1.0 : 2.0) / M);
    }

    apply_map<<<dim3(NBLK), dim3(NTHR), 0, stream>>>(grid, out, cf);
}

// Round 2
// 256.334 us; speedup vs baseline: 1.0066x; 1.0066x over previous
//
#include <hip/hip_runtime.h>
#include <math.h>

// FluidFlow: 20 Euler steps of g <- (g + (2/(W(1+g)+1)-1)*dt) * mask, N=6144.
// Analytically z == g+1, so the step is elementwise; the 20-step composite
// Phi(g) is a smooth scalar map on [0,1]. D(g)=Phi(g)-g is fit by a degree-5
// Chebyshev polynomial (coefficients decay ~7.3^-k; trunc error ~2e-7 vs the
// 2e-2 threshold), coefficients computed on the HOST at capture time.
//
// R2: hand-hoisted load batch. R1's rolled loop (VGPR=20) emitted
// load->waitcnt->compute->ntstore per iter; the next load's waitcnt sits
// AFTER the previous store in the vmcnt FIFO, so every iteration drained the
// NT store to HBM (3.34 TB/s measured). Here all 4 loads are issued first
// (oldest in FIFO); each compute's wait retires only its load, stores are
// newest and never waited on. 4 float4s/thread keeps VGPR < 64 (occupancy
// cliff at 64 per m69) -> 8 waves/SIMD, 32 KB/SIMD in flight.
// STRIDE/ROW4 = 1536 exactly: row-div once per thread, c4 invariant.

#define GN 6144
#define ROW4 (GN / 4)            // 1536 float4 per row
#define NCOEF 6                  // degree 5
#define TOTAL4 (GN * GN / 4)     // 9,437,184 float4s
#define NTHR 256
#define ITERS 4
#define NBLK (TOTAL4 / (NTHR * ITERS))  // 9216 blocks
#define STRIDE (NBLK * NTHR)            // 2,359,296 float4s
#define ROWSTEP (STRIDE / ROW4)         // 1536 rows (exact)

typedef float v4f __attribute__((ext_vector_type(4)));

struct Coeffs { float c[NCOEF]; };

__global__ __launch_bounds__(NTHR) void apply_map(const float* __restrict__ in,
                                                  float* __restrict__ out,
                                                  Coeffs cf) {
    const int tid = blockIdx.x * NTHR + threadIdx.x;
    const v4f* __restrict__ in4 = reinterpret_cast<const v4f*>(in);
    v4f* out4 = reinterpret_cast<v4f*>(out);

    // Batch all loads first: they are the OLDEST entries in the vmcnt FIFO,
    // so per-iter waits never require a store to drain.
    v4f v[ITERS];
#pragma unroll
    for (int i = 0; i < ITERS; ++i)
        v[i] = in4[tid + i * STRIDE];

    const int r0 = tid / ROW4;           // once per thread (magic-mul)
    const int c4 = tid - r0 * ROW4;      // float4-column, same for all i
    const bool left = (c4 == 0);
    const bool right = (c4 == ROW4 - 1);

#pragma unroll
    for (int i = 0; i < ITERS; ++i) {
        const int r = r0 + i * ROWSTEP;
        const bool row_int = (r > 0) && (r < GN - 1);

        v4f res;
#pragma unroll
        for (int j = 0; j < 4; ++j) {
            float g = v[i][j];
            float t = fmaf(2.0f, g, -1.0f);   // [0,1] -> [-1,1]
            float t2 = t + t;
            float b1 = 0.0f, b2 = 0.0f;
#pragma unroll
            for (int k = NCOEF - 1; k >= 1; --k) {
                float b0 = fmaf(t2, b1, cf.c[k] - b2);
                b2 = b1;
                b1 = b0;
            }
            float d = fmaf(t, b1, cf.c[0] - b2);
            res[j] = row_int ? (g + d) : 0.0f;
        }
        if (left)  res[0] = 0.0f;             // col 0
        if (right) res[3] = 0.0f;             // col GN-1
        __builtin_nontemporal_store(res, out4 + tid + i * STRIDE);
    }
}

// Host-side: 20-step Euler with Halley-12 Lambert W, reference-faithful, fp64.
static double phi_minus_g(double g0) {
    double g = g0;
    for (int s = 0; s < 20; ++s) {
        double xi = sqrt(2.0 * (log(g + 1.0) - 0.5 + 1.0));
        double z = exp(xi * xi * 0.5 + 0.5 - 1.0);
        double w = log1p(z);
        for (int it = 0; it < 12; ++it) {
            double ew = exp(w);
            double f = w * ew - z;
            w = w - f / (ew * (w + 1.0) - (w + 2.0) * f / (2.0 * w + 2.0));
        }
        g = g + (2.0 / (w + 1.0) - 1.0) * 0.01;
    }
    return g - g0;
}

extern "C" void kernel_launch(void* const* d_in, const int* in_sizes, int n_in,
                              void* d_out, int out_size, void* d_ws,
                              size_t ws_size, hipStream_t stream) {
    const float* grid = (const float*)d_in[0];
    float* out = (float*)d_out;

    // Project D onto Chebyshev basis with 32 nodes, keep first NCOEF coeffs
    // (near-best approximation; host fp64, deterministic, capture-time).
    const int M = 32;
    double dv[M];
    for (int j = 0; j < M; ++j) {
        double x = cos(M_PI * (j + 0.5) / M);
        dv[j] = phi_minus_g(0.5 * (x + 1.0));
    }
    Coeffs cf;
    for (int k = 0; k < NCOEF; ++k) {
        double s = 0.0;
        for (int j = 0; j < M; ++j)
            s += dv[j] * cos(M_PI * k * (j + 0.5) / M);
        cf.c[k] = (float)(s * (k == 0 ? 1.0 : 2.0) / M);
    }

    apply_map<<<dim3(NBLK), dim3(NTHR), 0, stream>>>(grid, out, cf);
}

// Round 3
// 255.265 us; speedup vs baseline: 1.0108x; 1.0042x over previous
//
#include <hip/hip_runtime.h>
#include <math.h>

// FluidFlow: 20 Euler steps of g <- (g + (2/(W(1+g)+1)-1)*dt) * mask, N=6144.
// Analytically z == g+1, so the step is elementwise; the 20-step composite
// Phi(g) is a smooth scalar map on [0,1]. D(g)=Phi(g)-g is fit by a degree-5
// Chebyshev polynomial (coefficients decay ~7.3^-k; trunc error ~2e-7 vs the
// 2e-2 threshold), coefficients computed on the HOST at capture time.
//
// R3: PLAIN stores (single variable vs R2). Evidence: R1 direct counters
// showed apply_map writing 151MB in 90.4us = 1.67 TB/s via nontemporal
// stores, while the rocclr fill kernel writes the same buffer at 6.7 TB/s
// through the normal L2/L3 write-back path. R2's max-MLP load batch was
// neutral end-to-end, falsifying the load-latency theory. The NT hint
// (inherited from the earlier session) bypasses L2/L3 and is the throttle;
// there is no write reuse to protect anyway.
// Keep R2's shape: 4 float4s/thread batched loads, 9216 blocks x 256.

#define GN 6144
#define ROW4 (GN / 4)            // 1536 float4 per row
#define NCOEF 6                  // degree 5
#define TOTAL4 (GN * GN / 4)     // 9,437,184 float4s
#define NTHR 256
#define ITERS 4
#define NBLK (TOTAL4 / (NTHR * ITERS))  // 9216 blocks
#define STRIDE (NBLK * NTHR)            // 2,359,296 float4s
#define ROWSTEP (STRIDE / ROW4)         // 1536 rows (exact)

typedef float v4f __attribute__((ext_vector_type(4)));

struct Coeffs { float c[NCOEF]; };

__global__ __launch_bounds__(NTHR) void apply_map(const float* __restrict__ in,
                                                  float* __restrict__ out,
                                                  Coeffs cf) {
    const int tid = blockIdx.x * NTHR + threadIdx.x;
    const v4f* __restrict__ in4 = reinterpret_cast<const v4f*>(in);
    v4f* out4 = reinterpret_cast<v4f*>(out);

    // Batch all loads first (oldest in the vmcnt FIFO).
    v4f v[ITERS];
#pragma unroll
    for (int i = 0; i < ITERS; ++i)
        v[i] = in4[tid + i * STRIDE];

    const int r0 = tid / ROW4;           // once per thread (magic-mul)
    const int c4 = tid - r0 * ROW4;      // float4-column, same for all i
    const bool left = (c4 == 0);
    const bool right = (c4 == ROW4 - 1);

#pragma unroll
    for (int i = 0; i < ITERS; ++i) {
        const int r = r0 + i * ROWSTEP;
        const bool row_int = (r > 0) && (r < GN - 1);

        v4f res;
#pragma unroll
        for (int j = 0; j < 4; ++j) {
            float g = v[i][j];
            float t = fmaf(2.0f, g, -1.0f);   // [0,1] -> [-1,1]
            float t2 = t + t;
            float b1 = 0.0f, b2 = 0.0f;
#pragma unroll
            for (int k = NCOEF - 1; k >= 1; --k) {
                float b0 = fmaf(t2, b1, cf.c[k] - b2);
                b2 = b1;
                b1 = b0;
            }
            float d = fmaf(t, b1, cf.c[0] - b2);
            res[j] = row_int ? (g + d) : 0.0f;
        }
        if (left)  res[0] = 0.0f;             // col 0
        if (right) res[3] = 0.0f;             // col GN-1
        out4[tid + i * STRIDE] = res;         // plain store: L2/L3 write-back
    }
}

// Host-side: 20-step Euler with Halley-12 Lambert W, reference-faithful, fp64.
static double phi_minus_g(double g0) {
    double g = g0;
    for (int s = 0; s < 20; ++s) {
        double xi = sqrt(2.0 * (log(g + 1.0) - 0.5 + 1.0));
        double z = exp(xi * xi * 0.5 + 0.5 - 1.0);
        double w = log1p(z);
        for (int it = 0; it < 12; ++it) {
            double ew = exp(w);
            double f = w * ew - z;
            w = w - f / (ew * (w + 1.0) - (w + 2.0) * f / (2.0 * w + 2.0));
        }
        g = g + (2.0 / (w + 1.0) - 1.0) * 0.01;
    }
    return g - g0;
}

extern "C" void kernel_launch(void* const* d_in, const int* in_sizes, int n_in,
                              void* d_out, int out_size, void* d_ws,
                              size_t ws_size, hipStream_t stream) {
    const float* grid = (const float*)d_in[0];
    float* out = (float*)d_out;

    // Project D onto Chebyshev basis with 32 nodes, keep first NCOEF coeffs
    // (near-best approximation; host fp64, deterministic, capture-time).
    const int M = 32;
    double dv[M];
    for (int j = 0; j < M; ++j) {
        double x = cos(M_PI * (j + 0.5) / M);
        dv[j] = phi_minus_g(0.5 * (x + 1.0));
    }
    Coeffs cf;
    for (int k = 0; k < NCOEF; ++k) {
        double s = 0.0;
        for (int j = 0; j < M; ++j)
            s += dv[j] * cos(M_PI * k * (j + 0.5) / M);
        cf.c[k] = (float)(s * (k == 0 ? 1.0 : 2.0) / M);
    }

    apply_map<<<dim3(NBLK), dim3(NTHR), 0, stream>>>(grid, out, cf);
}

// Round 4
// 245.175 us; speedup vs baseline: 1.0524x; 1.0412x over previous
//
#include <hip/hip_runtime.h>
#include <math.h>

// FluidFlow: 20 Euler steps of g <- (g + (2/(W(1+g)+1)-1)*dt) * mask, N=6144.
// Analytically z == g+1, so the step is elementwise; the 20-step composite
// Phi(g) is a smooth scalar map on [0,1]. D(g)=Phi(g)-g is fit by a degree-5
// Chebyshev polynomial (trunc error ~2e-7 vs the 2e-2 threshold),
// coefficients computed on the HOST at capture time.
//
// R4: completes the {shape}x{store} 2x2 matrix. Evidence so far:
//   1/thread + NT    = 247.1 (R0, best)
//   4/thread + NT    = 256.3 (R2)   4/thread + plain = 255.3 (R3)
// Store type is neutral (R2~R3); the ~8us penalty tracks the multi-per-
// thread shape. Mechanism: long waves end with s_waitcnt vmcnt(0) before
// s_endpgm holding 4 wave slots through the final store drain with no work
// left, while 1-float4 waves retire fast and the CU refills with fresh
// waves whose loads issue immediately. R4 = R0 shape + plain store (the
// untested cell, single variable vs R0).

#define GN 6144
#define ROW4 (GN / 4)   // 1536 float4 per row
#define NCOEF 6         // degree 5

typedef float v4f __attribute__((ext_vector_type(4)));

struct Coeffs { float c[NCOEF]; };

__global__ __launch_bounds__(256) void apply_map(const float* __restrict__ in,
                                                 float* __restrict__ out,
                                                 Coeffs cf) {
    const int idx = blockIdx.x * blockDim.x + threadIdx.x;  // exactly total4
    v4f v = reinterpret_cast<const v4f*>(in)[idx];

    const int r = idx / ROW4;             // row (magic-mul)
    const int c4 = idx - r * ROW4;        // float4-column
    const bool row_int = (r > 0) && (r < GN - 1);

    v4f res;
#pragma unroll
    for (int j = 0; j < 4; ++j) {
        float g = v[j];
        float t = fmaf(2.0f, g, -1.0f);   // [0,1] -> [-1,1]
        float t2 = t + t;
        float b1 = 0.0f, b2 = 0.0f;
#pragma unroll
        for (int k = NCOEF - 1; k >= 1; --k) {
            float b0 = fmaf(t2, b1, cf.c[k] - b2);
            b2 = b1;
            b1 = b0;
        }
        float d = fmaf(t, b1, cf.c[0] - b2);
        res[j] = row_int ? (g + d) : 0.0f;
    }
    if (c4 == 0) res[0] = 0.0f;           // col 0
    if (c4 == ROW4 - 1) res[3] = 0.0f;    // col GN-1
    reinterpret_cast<v4f*>(out)[idx] = res;   // plain store (R4 variable)
}

// Host-side: 20-step Euler with Halley-12 Lambert W, reference-faithful, fp64.
static double phi_minus_g(double g0) {
    double g = g0;
    for (int s = 0; s < 20; ++s) {
        double xi = sqrt(2.0 * (log(g + 1.0) - 0.5 + 1.0));
        double z = exp(xi * xi * 0.5 + 0.5 - 1.0);
        double w = log1p(z);
        for (int it = 0; it < 12; ++it) {
            double ew = exp(w);
            double f = w * ew - z;
            w = w - f / (ew * (w + 1.0) - (w + 2.0) * f / (2.0 * w + 2.0));
        }
        g = g + (2.0 / (w + 1.0) - 1.0) * 0.01;
    }
    return g - g0;
}

extern "C" void kernel_launch(void* const* d_in, const int* in_sizes, int n_in,
                              void* d_out, int out_size, void* d_ws,
                              size_t ws_size, hipStream_t stream) {
    const float* grid = (const float*)d_in[0];
    float* out = (float*)d_out;

    // Project D onto Chebyshev basis with 32 nodes, keep first NCOEF coeffs
    // (near-best approximation; host fp64, deterministic, capture-time).
    const int M = 32;
    double dv[M];
    for (int j = 0; j < M; ++j) {
        double x = cos(M_PI * (j + 0.5) / M);
        dv[j] = phi_minus_g(0.5 * (x + 1.0));
    }
    Coeffs cf;
    for (int k = 0; k < NCOEF; ++k) {
        double s = 0.0;
        for (int j = 0; j < M; ++j)
            s += dv[j] * cos(M_PI * k * (j + 0.5) / M);
        cf.c[k] = (float)(s * (k == 0 ? 1.0 : 2.0) / M);
    }

    const int total4 = GN * GN / 4;               // 9,437,184 float4s
    apply_map<<<dim3(total4 / 256), dim3(256), 0, stream>>>(grid, out, cf);
}